// Round 20
// baseline (209.521 us; speedup 1.0000x reference)
//
#include <hip/hip_runtime.h>
#include <hip/hip_bf16.h>
#include <cstdint>
#include <cstddef>

// Problem constants
#define B_ 8
#define N_ 2048
#define D_ 256
#define H_ 8
#define HD_ 32
#define LN_EPS 1e-5f
#define QSCALE 0.25506275f  // log2(e)/sqrt(32): folded into Q so p = exp2(q'.k)

typedef __attribute__((ext_vector_type(8))) short short8;
typedef __attribute__((ext_vector_type(4))) float f32x4;
typedef __attribute__((ext_vector_type(16))) float f32x16;

static __device__ __forceinline__ float exp2v(float x) {
#if __has_builtin(__builtin_amdgcn_exp2f)
    return __builtin_amdgcn_exp2f(x);
#else
    float r;
    asm("v_exp_f32 %0, %1" : "=v"(r) : "v"(x));
    return r;
#endif
}

static __device__ __forceinline__ unsigned short f2bf(float f) {
    union { float f; unsigned int u; } v; v.f = f;
    unsigned int r = v.u + 0x7fffu + ((v.u >> 16) & 1u);
    return (unsigned short)(r >> 16);
}

static __device__ __forceinline__ unsigned int cvtpk(float lo, float hi) {
    unsigned int d;
    asm("v_cvt_pk_bf16_f32 %0, %1, %2" : "=v"(d) : "v"(lo), "v"(hi));
    return d;
}

// ---------------- prep: W fp32 -> bf16 transposed wt[mat][col][k] ----------------
__global__ __launch_bounds__(256) void k_prep_w(const float* __restrict__ w0, const float* __restrict__ w1,
                                                const float* __restrict__ w2, const float* __restrict__ w3,
                                                unsigned short* __restrict__ wt) {
    int c = blockIdx.x, mat = blockIdx.y, k = threadIdx.x;
    const float* w = (mat == 0) ? w0 : (mat == 1) ? w1 : (mat == 2) ? w2 : w3;
    wt[((size_t)(mat * 256 + c)) * 256 + k] = f2bf(w[k * 256 + c]);
}

// ---------------- FUSED adjacency -> transposed lane-mask (512 thr, 8 waves) ----------------
__global__ __launch_bounds__(512) void k_maskF(const int* __restrict__ adj,
                                               unsigned int* __restrict__ mbgT2) {
    __shared__ unsigned int bits[64][66];
    int tid = threadIdx.x, lane = tid & 63, wv = tid >> 6;   // wv 0..7
    int b = blockIdx.x >> 5, rg = blockIdx.x & 31;

    const int* base = adj + ((size_t)(b * N_ + rg * 64 + wv * 8)) * N_ + lane;
#pragma unroll 1
    for (int i = 0; i < 8; ++i) {
        const int* prow = base + (size_t)i * N_;
#pragma unroll
        for (int half = 0; half < 2; ++half) {
            int v[16];
#pragma unroll
            for (int j = 0; j < 16; ++j)
                v[j] = prow[half * 1024 + j * 64];
            __builtin_amdgcn_sched_barrier(0);
#pragma unroll
            for (int j = 0; j < 16; ++j) {
                unsigned long long m = __ballot(v[j] != 0);
                if (lane == 0)
                    *reinterpret_cast<unsigned long long*>(&bits[wv * 8 + i][half * 32 + 2 * j]) = m;
            }
        }
    }
    __syncthreads();

    int h = lane >> 5, l31 = lane & 31;
    const unsigned int M[5] = {0x0000FFFFu, 0x00FF00FFu, 0x0F0F0F0Fu, 0x33333333u, 0x55555555u};
#pragma unroll
    for (int j = 0; j < 8; ++j) {
        int kw = wv * 8 + j;
        unsigned int w = bits[lane][kw];
#pragma unroll
        for (int si = 0; si < 5; ++si) {
            int s = 16 >> si;
            unsigned int m = M[si];
            unsigned int t = (unsigned int)__shfl_xor((int)w, s, 64);
            unsigned int a = (w & m) | ((t & m) << s);
            unsigned int c = (w & ~m) | ((t >> s) & m);
            w = (lane & s) ? c : a;
        }
        int k = kw * 32 + l31;
        int kp = (k & ~7) | ((k & 3) << 1) | ((k >> 2) & 1);
        mbgT2[((size_t)(b * 64 + rg * 2 + h)) * 2048 + kp] = w;
    }
}

// ---------------- fused QKV projection GEMM ----------------
__global__ __launch_bounds__(256) void k_qkv(const float* __restrict__ x,
                                             const unsigned short* __restrict__ wt,
                                             const float* __restrict__ bq, const float* __restrict__ bk,
                                             const float* __restrict__ bv,
                                             unsigned short* __restrict__ Qts, unsigned short* __restrict__ Ks,
                                             unsigned short* __restrict__ Vs) {
    int mat = blockIdx.y;
    int lane = threadIdx.x & 63;
    int wv = threadIdx.x >> 6;
    int row0 = blockIdx.x * 64 + wv * 16;
    int l15 = lane & 15, lg = lane >> 4;
    const float* bias = (mat == 0) ? bq : (mat == 1) ? bk : bv;
    const float qs = (mat == 0) ? QSCALE : 1.0f;
    const unsigned short* wm = wt + (size_t)mat * 65536;

    short8 af[8];
    const float* xrow = x + (size_t)(row0 + l15) * 256 + lg * 8;
#pragma unroll
    for (int kk = 0; kk < 8; ++kk) {
        float4 a = *reinterpret_cast<const float4*>(xrow + kk * 32);
        float4 b = *reinterpret_cast<const float4*>(xrow + kk * 32 + 4);
        union { short8 s8; unsigned int u[4]; } t;
        t.u[0] = cvtpk(a.x, a.y); t.u[1] = cvtpk(a.z, a.w);
        t.u[2] = cvtpk(b.x, b.y); t.u[3] = cvtpk(b.z, b.w);
        af[kk] = t.s8;
    }

    int b = row0 >> 11;            // 2048 rows per batch; 64-row blocks never cross
    int nbase = (row0 & 2047) + lg * 4;

    if (mat < 2) {
        unsigned short* dst = (mat == 0) ? Qts : Ks;
        int n = (row0 & 2047) + l15;          // lane's row
        for (int ci = 0; ci < 16; ++ci) {
            const unsigned short* wrow = wm + (size_t)(ci * 16 + l15) * 256 + lg * 8;
            f32x4 acc = {0.f, 0.f, 0.f, 0.f};
#pragma unroll
            for (int kk = 0; kk < 8; ++kk) {
                short8 bfg = *reinterpret_cast<const short8*>(wrow + kk * 32);
                acc = __builtin_amdgcn_mfma_f32_16x16x32_bf16(bfg, af[kk], acc, 0, 0, 0);
            }
            int col0 = ci * 16 + lg * 4;
            float4 b4 = *reinterpret_cast<const float4*>(bias + col0);
            int h = col0 >> 5;
            int hd0 = col0 & 31;
            size_t off = (size_t)(b * 8 + h) * 65536 + (size_t)(n >> 5) * 1024
                       + (size_t)(hd0 >> 4) * 512
                       + (size_t)((((hd0 >> 3) & 1) * 32 + (n & 31))) * 8 + (hd0 & 7);
            ushort4 o;
            o.x = f2bf((acc[0] + b4.x) * qs); o.y = f2bf((acc[1] + b4.y) * qs);
            o.z = f2bf((acc[2] + b4.z) * qs); o.w = f2bf((acc[3] + b4.w) * qs);
            *reinterpret_cast<ushort4*>(dst + off) = o;
        }
    } else {
        for (int ci = 0; ci < 16; ++ci) {
            const unsigned short* wrow = wm + (size_t)(ci * 16 + l15) * 256 + lg * 8;
            f32x4 acc = {0.f, 0.f, 0.f, 0.f};
#pragma unroll
            for (int kk = 0; kk < 8; ++kk) {
                short8 bfg = *reinterpret_cast<const short8*>(wrow + kk * 32);
                acc = __builtin_amdgcn_mfma_f32_16x16x32_bf16(af[kk], bfg, acc, 0, 0, 0);
            }
            int col = ci * 16 + l15;
            float bcol = bias[col];
            int h = col >> 5, hd = col & 31;
            int posb = nbase & 31;
            size_t off = (size_t)(b * 8 + h) * 65536 + (size_t)(nbase >> 5) * 1024
                       + (posb >> 4) * 512 + ((((posb >> 3) & 1) * 32 + hd)) * 8 + (posb & 7);
            ushort4 o;
            o.x = f2bf(acc[0] + bcol); o.y = f2bf(acc[1] + bcol);
            o.z = f2bf(acc[2] + bcol); o.w = f2bf(acc[3] + bcol);
            *reinterpret_cast<ushort4*>(Vs + off) = o;
        }
    }
}

#define SLA(j, offs) asm("s_load_dwordx2 %0, %1, " offs : "=s"(ma##j) : "s"(mbaseA))
#define SLOADA16() do { \
    SLA(0, "0x0");  SLA(1, "0x8");  SLA(2, "0x10"); SLA(3, "0x18"); \
    SLA(4, "0x20"); SLA(5, "0x28"); SLA(6, "0x30"); SLA(7, "0x38"); \
    SLA(8, "0x40"); SLA(9, "0x48"); SLA(10, "0x50"); SLA(11, "0x58"); \
    SLA(12, "0x60"); SLA(13, "0x68"); SLA(14, "0x70"); SLA(15, "0x78"); } while (0)
#define SLB(j, offs) asm("s_load_dwordx2 %0, %1, " offs : "=s"(mb##j) : "s"(mbaseB))
#define SLOADB16() do { \
    SLB(0, "0x0");  SLB(1, "0x8");  SLB(2, "0x10"); SLB(3, "0x18"); \
    SLB(4, "0x20"); SLB(5, "0x28"); SLB(6, "0x30"); SLB(7, "0x38"); \
    SLB(8, "0x40"); SLB(9, "0x48"); SLB(10, "0x50"); SLB(11, "0x58"); \
    SLB(12, "0x60"); SLB(13, "0x68"); SLB(14, "0x70"); SLB(15, "0x78"); } while (0)
#define CND(d, s_, mj) asm("v_cndmask_b32 %0, 0, %1, %2" : "=v"(d) : "v"(s_), "s"(mj))

// ---------------- masked attention (2 q-tiles per wave) ----------------
// grid 512: b = blk&7 (XCD), hg = (blk>>3)&1, qt64 = blk>>4; wave = head,
// processes q-tiles qtA = 2*qt64 and qtB = qtA+1. K/V fragments loaded ONCE
// per iter feed both q-tiles' QK and PV MFMAs -> K/V + addressing load
// traffic per output halves (the kernel's 40% stall is load-side). Order
// QK(A,B) -> softmax A -> PV A -> softmax B -> PV B overlaps PV-A's MFMA
// with softmax-B's VALU. Masks: two scalar streams (s_load_dwordx2).
__global__ __launch_bounds__(256, 4) void k_attn(const unsigned short* __restrict__ Qts,
                                                 const unsigned short* __restrict__ Kb,
                                                 const unsigned short* __restrict__ Vs,
                                                 const unsigned int* __restrict__ mbgT2,
                                                 unsigned short* __restrict__ att) {
    int tid = threadIdx.x;
    int lane = tid & 63;
    int l31 = lane & 31, hi = lane >> 5;
    int b = blockIdx.x & 7;
    int hg = (blockIdx.x >> 3) & 1;
    int qt64 = blockIdx.x >> 4;          // 0..31
    int qtA = qt64 * 2;
    int head = hg * 4 + (tid >> 6);
    int bh = b * 8 + head;

    const unsigned short* QhA = Qts + (size_t)bh * 65536 + (size_t)qtA * 1024 + (size_t)lane * 8;
    const unsigned short* Kh = Kb + (size_t)bh * 65536;
    const unsigned short* Vh = Vs + (size_t)bh * 65536;

    short8 qfA0 = *reinterpret_cast<const short8*>(QhA);
    short8 qfA1 = *reinterpret_cast<const short8*>(QhA + 512);
    short8 qfB0 = *reinterpret_cast<const short8*>(QhA + 1024);
    short8 qfB1 = *reinterpret_cast<const short8*>(QhA + 1536);
    const unsigned short* krow = Kh + (size_t)lane * 8;
    const unsigned short* vfp = Vh + (size_t)lane * 8;

    unsigned long long mbaseA = (unsigned long long)(mbgT2 + (size_t)(b * 64 + qtA) * 2048);
    unsigned long long mbaseB = mbaseA + 8192;
    unsigned long long ma0, ma1, ma2, ma3, ma4, ma5, ma6, ma7, ma8, ma9, ma10, ma11, ma12, ma13, ma14, ma15;
    unsigned long long mb0, mb1, mb2, mb3, mb4, mb5, mb6, mb7, mb8, mb9, mb10, mb11, mb12, mb13, mb14, mb15;
    SLOADA16();
    SLOADB16();

    const f32x16 fz = {0.f,0.f,0.f,0.f,0.f,0.f,0.f,0.f,0.f,0.f,0.f,0.f,0.f,0.f,0.f,0.f};
    f32x16 attaccA = fz, attaccB = fz;
    float lsumA = 0.f, lsumB = 0.f;

#pragma unroll 1
    for (int t = 0; t < 64; ++t) {
        short8 kf0 = *reinterpret_cast<const short8*>(krow + (size_t)t * 1024);
        short8 kf1 = *reinterpret_cast<const short8*>(krow + (size_t)t * 1024 + 512);
        short8 vf0 = *reinterpret_cast<const short8*>(vfp + (size_t)t * 1024);
        short8 vf1 = *reinterpret_cast<const short8*>(vfp + (size_t)t * 1024 + 512);

        f32x16 sA = __builtin_amdgcn_mfma_f32_32x32x16_bf16(kf0, qfA0, fz, 0, 0, 0);
        sA = __builtin_amdgcn_mfma_f32_32x32x16_bf16(kf1, qfA1, sA, 0, 0, 0);
        f32x16 sB = __builtin_amdgcn_mfma_f32_32x32x16_bf16(kf0, qfB0, fz, 0, 0, 0);
        sB = __builtin_amdgcn_mfma_f32_32x32x16_bf16(kf1, qfB1, sB, 0, 0, 0);

        // ---- softmax + PV for tile A ----
        {
            float e0 = exp2v(sA[0]),  e1 = exp2v(sA[1]),  e2 = exp2v(sA[2]),  e3 = exp2v(sA[3]);
            float e4 = exp2v(sA[4]),  e5 = exp2v(sA[5]),  e6 = exp2v(sA[6]),  e7 = exp2v(sA[7]);
            float e8 = exp2v(sA[8]),  e9 = exp2v(sA[9]),  e10 = exp2v(sA[10]), e11 = exp2v(sA[11]);
            float e12 = exp2v(sA[12]), e13 = exp2v(sA[13]), e14 = exp2v(sA[14]), e15 = exp2v(sA[15]);

            asm volatile("s_waitcnt lgkmcnt(0)"
                         : "+s"(ma0), "+s"(ma1), "+s"(ma2), "+s"(ma3), "+s"(ma4), "+s"(ma5), "+s"(ma6), "+s"(ma7),
                           "+s"(ma8), "+s"(ma9), "+s"(ma10), "+s"(ma11), "+s"(ma12), "+s"(ma13), "+s"(ma14), "+s"(ma15));

            float p0, p1, p2, p3, p4, p5, p6, p7, p8, p9, p10, p11, p12, p13, p14, p15;
            CND(p0, e0, ma0);   CND(p1, e1, ma1);   CND(p2, e2, ma2);   CND(p3, e3, ma3);
            CND(p4, e4, ma4);   CND(p5, e5, ma5);   CND(p6, e6, ma6);   CND(p7, e7, ma7);
            CND(p8, e8, ma8);   CND(p9, e9, ma9);   CND(p10, e10, ma10); CND(p11, e11, ma11);
            CND(p12, e12, ma12); CND(p13, e13, ma13); CND(p14, e14, ma14); CND(p15, e15, ma15);

            lsumA += ((p0 + p1) + (p2 + p3)) + ((p4 + p5) + (p6 + p7))
                   + ((p8 + p9) + (p10 + p11)) + ((p12 + p13) + (p14 + p15));

            unsigned int pd[4][2];
            pd[0][0] = cvtpk(p0, p1);   pd[0][1] = cvtpk(p2, p3);
            pd[1][0] = cvtpk(p4, p5);   pd[1][1] = cvtpk(p6, p7);
            pd[2][0] = cvtpk(p8, p9);   pd[2][1] = cvtpk(p10, p11);
            pd[3][0] = cvtpk(p12, p13); pd[3][1] = cvtpk(p14, p15);

            mbaseA += 128;
            SLOADA16();

            asm("v_permlane32_swap_b32 %0, %1" : "+v"(pd[0][0]), "+v"(pd[1][0]));
            asm("v_permlane32_swap_b32 %0, %1" : "+v"(pd[0][1]), "+v"(pd[1][1]));
            asm("v_permlane32_swap_b32 %0, %1" : "+v"(pd[2][0]), "+v"(pd[3][0]));
            asm("v_permlane32_swap_b32 %0, %1" : "+v"(pd[2][1]), "+v"(pd[3][1]));

            union { short8 s8; unsigned int u[4]; } bf0, bf1;
            bf0.u[0] = pd[0][0]; bf0.u[1] = pd[0][1]; bf0.u[2] = pd[1][0]; bf0.u[3] = pd[1][1];
            bf1.u[0] = pd[2][0]; bf1.u[1] = pd[2][1]; bf1.u[2] = pd[3][0]; bf1.u[3] = pd[3][1];

            attaccA = __builtin_amdgcn_mfma_f32_32x32x16_bf16(vf0, bf0.s8, attaccA, 0, 0, 0);
            attaccA = __builtin_amdgcn_mfma_f32_32x32x16_bf16(vf1, bf1.s8, attaccA, 0, 0, 0);
        }

        // ---- softmax + PV for tile B ----
        {
            float e0 = exp2v(sB[0]),  e1 = exp2v(sB[1]),  e2 = exp2v(sB[2]),  e3 = exp2v(sB[3]);
            float e4 = exp2v(sB[4]),  e5 = exp2v(sB[5]),  e6 = exp2v(sB[6]),  e7 = exp2v(sB[7]);
            float e8 = exp2v(sB[8]),  e9 = exp2v(sB[9]),  e10 = exp2v(sB[10]), e11 = exp2v(sB[11]);
            float e12 = exp2v(sB[12]), e13 = exp2v(sB[13]), e14 = exp2v(sB[14]), e15 = exp2v(sB[15]);

            float p0, p1, p2, p3, p4, p5, p6, p7, p8, p9, p10, p11, p12, p13, p14, p15;
            CND(p0, e0, mb0);   CND(p1, e1, mb1);   CND(p2, e2, mb2);   CND(p3, e3, mb3);
            CND(p4, e4, mb4);   CND(p5, e5, mb5);   CND(p6, e6, mb6);   CND(p7, e7, mb7);
            CND(p8, e8, mb8);   CND(p9, e9, mb9);   CND(p10, e10, mb10); CND(p11, e11, mb11);
            CND(p12, e12, mb12); CND(p13, e13, mb13); CND(p14, e14, mb14); CND(p15, e15, mb15);

            lsumB += ((p0 + p1) + (p2 + p3)) + ((p4 + p5) + (p6 + p7))
                   + ((p8 + p9) + (p10 + p11)) + ((p12 + p13) + (p14 + p15));

            unsigned int pd[4][2];
            pd[0][0] = cvtpk(p0, p1);   pd[0][1] = cvtpk(p2, p3);
            pd[1][0] = cvtpk(p4, p5);   pd[1][1] = cvtpk(p6, p7);
            pd[2][0] = cvtpk(p8, p9);   pd[2][1] = cvtpk(p10, p11);
            pd[3][0] = cvtpk(p12, p13); pd[3][1] = cvtpk(p14, p15);

            mbaseB += 128;
            SLOADB16();

            asm("v_permlane32_swap_b32 %0, %1" : "+v"(pd[0][0]), "+v"(pd[1][0]));
            asm("v_permlane32_swap_b32 %0, %1" : "+v"(pd[0][1]), "+v"(pd[1][1]));
            asm("v_permlane32_swap_b32 %0, %1" : "+v"(pd[2][0]), "+v"(pd[3][0]));
            asm("v_permlane32_swap_b32 %0, %1" : "+v"(pd[2][1]), "+v"(pd[3][1]));

            union { short8 s8; unsigned int u[4]; } bf0, bf1;
            bf0.u[0] = pd[0][0]; bf0.u[1] = pd[0][1]; bf0.u[2] = pd[1][0]; bf0.u[3] = pd[1][1];
            bf1.u[0] = pd[2][0]; bf1.u[1] = pd[2][1]; bf1.u[2] = pd[3][0]; bf1.u[3] = pd[3][1];

            attaccB = __builtin_amdgcn_mfma_f32_32x32x16_bf16(vf0, bf0.s8, attaccB, 0, 0, 0);
            attaccB = __builtin_amdgcn_mfma_f32_32x32x16_bf16(vf1, bf1.s8, attaccB, 0, 0, 0);
        }
    }

    lsumA += __shfl_xor(lsumA, 32, 64);
    lsumB += __shfl_xor(lsumB, 32, 64);
    float rcpA = 1.f / lsumA;
    float rcpB = 1.f / lsumB;

    unsigned short* arowA = att + ((size_t)b * N_ + qtA * 32 + l31) * D_ + head * HD_;
    unsigned short* arowB = arowA + 32 * D_;
#pragma unroll
    for (int g = 0; g < 4; ++g) {
        ushort4 oA, oB;
        oA.x = f2bf(attaccA[4 * g + 0] * rcpA);
        oA.y = f2bf(attaccA[4 * g + 1] * rcpA);
        oA.z = f2bf(attaccA[4 * g + 2] * rcpA);
        oA.w = f2bf(attaccA[4 * g + 3] * rcpA);
        oB.x = f2bf(attaccB[4 * g + 0] * rcpB);
        oB.y = f2bf(attaccB[4 * g + 1] * rcpB);
        oB.z = f2bf(attaccB[4 * g + 2] * rcpB);
        oB.w = f2bf(attaccB[4 * g + 3] * rcpB);
        *reinterpret_cast<ushort4*>(arowA + 8 * g + 4 * hi) = oA;
        *reinterpret_cast<ushort4*>(arowB + 8 * g + 4 * hi) = oB;
    }
}

// ---------------- out projection + residual + LayerNorm (vectorized) ----------------
__global__ __launch_bounds__(256) void k_outln(const unsigned short* __restrict__ att,
                                               const unsigned short* __restrict__ wot,
                                               const float* __restrict__ bo,
                                               const float* __restrict__ x,
                                               const float* __restrict__ gamma, const float* __restrict__ beta,
                                               float* __restrict__ out) {
    int lane = threadIdx.x & 63, wv = threadIdx.x >> 6;
    int l15 = lane & 15, lg = lane >> 4;
    int row0 = blockIdx.x * 64 + wv * 16;
    size_t row = (size_t)(row0 + l15);

    short8 af[8];
    const unsigned short* arow = att + row * 256 + lg * 8;
#pragma unroll
    for (int kk = 0; kk < 8; ++kk)
        af[kk] = *reinterpret_cast<const short8*>(arow + kk * 32);

    float v[16][4];
    float sum = 0.f, sq = 0.f;
#pragma unroll
    for (int ci = 0; ci < 16; ++ci) {
        const unsigned short* wrow = wot + (size_t)(ci * 16 + l15) * 256 + lg * 8;
        f32x4 acc = {0.f, 0.f, 0.f, 0.f};
#pragma unroll
        for (int kk = 0; kk < 8; ++kk) {
            short8 bfg = *reinterpret_cast<const short8*>(wrow + kk * 32);
            acc = __builtin_amdgcn_mfma_f32_16x16x32_bf16(bfg, af[kk], acc, 0, 0, 0);
        }
        int col0 = ci * 16 + lg * 4;
        float4 b4 = *reinterpret_cast<const float4*>(bo + col0);
        float4 x4 = *reinterpret_cast<const float4*>(x + row * 256 + col0);
        v[ci][0] = acc[0] + b4.x + x4.x;
        v[ci][1] = acc[1] + b4.y + x4.y;
        v[ci][2] = acc[2] + b4.z + x4.z;
        v[ci][3] = acc[3] + b4.w + x4.w;
#pragma unroll
        for (int r = 0; r < 4; ++r) {
            sum += v[ci][r];
            sq += v[ci][r] * v[ci][r];
        }
    }

    sum += __shfl_xor(sum, 16, 64); sq += __shfl_xor(sq, 16, 64);
    sum += __shfl_xor(sum, 32, 64); sq += __shfl_xor(sq, 32, 64);

    float mu = sum * (1.f / 256.f);
    float var = sq * (1.f / 256.f) - mu * mu;
    float rs = rsqrtf(var + LN_EPS);

#pragma unroll
    for (int ci = 0; ci < 16; ++ci) {
        int col0 = ci * 16 + lg * 4;
        float4 g4 = *reinterpret_cast<const float4*>(gamma + col0);
        float4 be4 = *reinterpret_cast<const float4*>(beta + col0);
        float4 o;
        o.x = (v[ci][0] - mu) * rs * g4.x + be4.x;
        o.y = (v[ci][1] - mu) * rs * g4.y + be4.y;
        o.z = (v[ci][2] - mu) * rs * g4.z + be4.z;
        o.w = (v[ci][3] - mu) * rs * g4.w + be4.w;
        *reinterpret_cast<float4*>(out + row * 256 + col0) = o;
    }
}

extern "C" void kernel_launch(void* const* d_in, const int* in_sizes, int n_in,
                              void* d_out, int out_size, void* d_ws, size_t ws_size,
                              hipStream_t stream) {
    (void)in_sizes; (void)n_in; (void)out_size; (void)ws_size;
    const float* x     = (const float*)d_in[0];
    const int*   adj   = (const int*)d_in[1];
    const float* Wq    = (const float*)d_in[2];
    const float* bq    = (const float*)d_in[3];
    const float* Wk    = (const float*)d_in[4];
    const float* bk    = (const float*)d_in[5];
    const float* Wv    = (const float*)d_in[6];
    const float* bv    = (const float*)d_in[7];
    const float* Wo    = (const float*)d_in[8];
    const float* bo    = (const float*)d_in[9];
    const float* gamma = (const float*)d_in[10];
    const float* beta  = (const float*)d_in[11];
    float* out = (float*)d_out;

    char* ws = (char*)d_ws;
    unsigned short* wt   = (unsigned short*)ws; ws += (size_t)4 * 256 * 256 * 2; // 0.5 MB
    unsigned short* Qts  = (unsigned short*)ws; ws += (size_t)B_ * H_ * N_ * HD_ * 2; // 8.4 MB
    unsigned short* Ks   = (unsigned short*)ws; ws += (size_t)B_ * H_ * N_ * HD_ * 2;
    unsigned short* Vs   = (unsigned short*)ws; ws += (size_t)B_ * H_ * N_ * HD_ * 2;
    unsigned short* att  = (unsigned short*)ws; ws += (size_t)16384 * 256 * 2;
    unsigned int*   mbgT2 = (unsigned int*)ws;  ws += (size_t)B_ * 64 * 2048 * 4 + 16384; // 4.2 MB + pad

    k_prep_w<<<dim3(256, 4), 256, 0, stream>>>(Wq, Wk, Wv, Wo, wt);
    k_maskF<<<256, 512, 0, stream>>>(adj, mbgT2);
    k_qkv<<<dim3(256, 3), 256, 0, stream>>>(x, wt, bq, bk, bv, Qts, Ks, Vs);
    k_attn<<<512, 256, 0, stream>>>(Qts, Ks, Vs, mbgT2, att);
    k_outln<<<256, 256, 0, stream>>>(att, wt + 3 * 65536, bo, x, gamma, beta, out);
}

// Round 21
// 175.961 us; speedup vs baseline: 1.1907x; 1.1907x over previous
//
#include <hip/hip_runtime.h>
#include <hip/hip_bf16.h>
#include <cstdint>
#include <cstddef>

// Problem constants
#define B_ 8
#define N_ 2048
#define D_ 256
#define H_ 8
#define HD_ 32
#define LN_EPS 1e-5f
#define QSCALE 0.25506275f  // log2(e)/sqrt(32): folded into Q so p = exp2(q'.k)

typedef __attribute__((ext_vector_type(8))) short short8;
typedef __attribute__((ext_vector_type(4))) float f32x4;
typedef __attribute__((ext_vector_type(16))) float f32x16;

static __device__ __forceinline__ float exp2v(float x) {
#if __has_builtin(__builtin_amdgcn_exp2f)
    return __builtin_amdgcn_exp2f(x);
#else
    float r;
    asm("v_exp_f32 %0, %1" : "=v"(r) : "v"(x));
    return r;
#endif
}

static __device__ __forceinline__ unsigned short f2bf(float f) {
    union { float f; unsigned int u; } v; v.f = f;
    unsigned int r = v.u + 0x7fffu + ((v.u >> 16) & 1u);
    return (unsigned short)(r >> 16);
}

static __device__ __forceinline__ unsigned int cvtpk(float lo, float hi) {
    unsigned int d;
    asm("v_cvt_pk_bf16_f32 %0, %1, %2" : "=v"(d) : "v"(lo), "v"(hi));
    return d;
}

// ---------------- prep: W fp32 -> bf16 transposed wt[mat][col][k] ----------------
__global__ __launch_bounds__(256) void k_prep_w(const float* __restrict__ w0, const float* __restrict__ w1,
                                                const float* __restrict__ w2, const float* __restrict__ w3,
                                                unsigned short* __restrict__ wt) {
    int c = blockIdx.x, mat = blockIdx.y, k = threadIdx.x;
    const float* w = (mat == 0) ? w0 : (mat == 1) ? w1 : (mat == 2) ? w2 : w3;
    wt[((size_t)(mat * 256 + c)) * 256 + k] = f2bf(w[k * 256 + c]);
}

// ---------------- FUSED adjacency -> transposed lane-mask (512 thr, 8 waves) ----------------
__global__ __launch_bounds__(512) void k_maskF(const int* __restrict__ adj,
                                               unsigned int* __restrict__ mbgT2) {
    __shared__ unsigned int bits[64][66];
    int tid = threadIdx.x, lane = tid & 63, wv = tid >> 6;   // wv 0..7
    int b = blockIdx.x >> 5, rg = blockIdx.x & 31;

    const int* base = adj + ((size_t)(b * N_ + rg * 64 + wv * 8)) * N_ + lane;
#pragma unroll 1
    for (int i = 0; i < 8; ++i) {
        const int* prow = base + (size_t)i * N_;
#pragma unroll
        for (int half = 0; half < 2; ++half) {
            int v[16];
#pragma unroll
            for (int j = 0; j < 16; ++j)
                v[j] = prow[half * 1024 + j * 64];
            __builtin_amdgcn_sched_barrier(0);
#pragma unroll
            for (int j = 0; j < 16; ++j) {
                unsigned long long m = __ballot(v[j] != 0);
                if (lane == 0)
                    *reinterpret_cast<unsigned long long*>(&bits[wv * 8 + i][half * 32 + 2 * j]) = m;
            }
        }
    }
    __syncthreads();

    int h = lane >> 5, l31 = lane & 31;
    const unsigned int M[5] = {0x0000FFFFu, 0x00FF00FFu, 0x0F0F0F0Fu, 0x33333333u, 0x55555555u};
#pragma unroll
    for (int j = 0; j < 8; ++j) {
        int kw = wv * 8 + j;
        unsigned int w = bits[lane][kw];
#pragma unroll
        for (int si = 0; si < 5; ++si) {
            int s = 16 >> si;
            unsigned int m = M[si];
            unsigned int t = (unsigned int)__shfl_xor((int)w, s, 64);
            unsigned int a = (w & m) | ((t & m) << s);
            unsigned int c = (w & ~m) | ((t >> s) & m);
            w = (lane & s) ? c : a;
        }
        int k = kw * 32 + l31;
        int kp = (k & ~7) | ((k & 3) << 1) | ((k >> 2) & 1);
        mbgT2[((size_t)(b * 64 + rg * 2 + h)) * 2048 + kp] = w;
    }
}

// ---------------- fused QKV projection GEMM ----------------
__global__ __launch_bounds__(256) void k_qkv(const float* __restrict__ x,
                                             const unsigned short* __restrict__ wt,
                                             const float* __restrict__ bq, const float* __restrict__ bk,
                                             const float* __restrict__ bv,
                                             unsigned short* __restrict__ Qts, unsigned short* __restrict__ Ks,
                                             unsigned short* __restrict__ Vs) {
    int mat = blockIdx.y;
    int lane = threadIdx.x & 63;
    int wv = threadIdx.x >> 6;
    int row0 = blockIdx.x * 64 + wv * 16;
    int l15 = lane & 15, lg = lane >> 4;
    const float* bias = (mat == 0) ? bq : (mat == 1) ? bk : bv;
    const float qs = (mat == 0) ? QSCALE : 1.0f;
    const unsigned short* wm = wt + (size_t)mat * 65536;

    short8 af[8];
    const float* xrow = x + (size_t)(row0 + l15) * 256 + lg * 8;
#pragma unroll
    for (int kk = 0; kk < 8; ++kk) {
        float4 a = *reinterpret_cast<const float4*>(xrow + kk * 32);
        float4 b = *reinterpret_cast<const float4*>(xrow + kk * 32 + 4);
        union { short8 s8; unsigned int u[4]; } t;
        t.u[0] = cvtpk(a.x, a.y); t.u[1] = cvtpk(a.z, a.w);
        t.u[2] = cvtpk(b.x, b.y); t.u[3] = cvtpk(b.z, b.w);
        af[kk] = t.s8;
    }

    int b = row0 >> 11;            // 2048 rows per batch; 64-row blocks never cross
    int nbase = (row0 & 2047) + lg * 4;

    if (mat < 2) {
        unsigned short* dst = (mat == 0) ? Qts : Ks;
        int n = (row0 & 2047) + l15;          // lane's row
        for (int ci = 0; ci < 16; ++ci) {
            const unsigned short* wrow = wm + (size_t)(ci * 16 + l15) * 256 + lg * 8;
            f32x4 acc = {0.f, 0.f, 0.f, 0.f};
#pragma unroll
            for (int kk = 0; kk < 8; ++kk) {
                short8 bfg = *reinterpret_cast<const short8*>(wrow + kk * 32);
                acc = __builtin_amdgcn_mfma_f32_16x16x32_bf16(bfg, af[kk], acc, 0, 0, 0);
            }
            // acc[r] = M[row0+l15][ci*16 + lg*4 + r]
            int col0 = ci * 16 + lg * 4;
            float4 b4 = *reinterpret_cast<const float4*>(bias + col0);
            int h = col0 >> 5;
            int hd0 = col0 & 31;
            size_t off = (size_t)(b * 8 + h) * 65536 + (size_t)(n >> 5) * 1024
                       + (size_t)(hd0 >> 4) * 512
                       + (size_t)((((hd0 >> 3) & 1) * 32 + (n & 31))) * 8 + (hd0 & 7);
            ushort4 o;
            o.x = f2bf((acc[0] + b4.x) * qs); o.y = f2bf((acc[1] + b4.y) * qs);
            o.z = f2bf((acc[2] + b4.z) * qs); o.w = f2bf((acc[3] + b4.w) * qs);
            *reinterpret_cast<ushort4*>(dst + off) = o;
        }
    } else {
        for (int ci = 0; ci < 16; ++ci) {
            const unsigned short* wrow = wm + (size_t)(ci * 16 + l15) * 256 + lg * 8;
            f32x4 acc = {0.f, 0.f, 0.f, 0.f};
#pragma unroll
            for (int kk = 0; kk < 8; ++kk) {
                short8 bfg = *reinterpret_cast<const short8*>(wrow + kk * 32);
                acc = __builtin_amdgcn_mfma_f32_16x16x32_bf16(af[kk], bfg, acc, 0, 0, 0);
            }
            int col = ci * 16 + l15;
            float bcol = bias[col];
            int h = col >> 5, hd = col & 31;
            int posb = nbase & 31;
            size_t off = (size_t)(b * 8 + h) * 65536 + (size_t)(nbase >> 5) * 1024
                       + (posb >> 4) * 512 + ((((posb >> 3) & 1) * 32 + hd)) * 8 + (posb & 7);
            ushort4 o;
            o.x = f2bf(acc[0] + bcol); o.y = f2bf(acc[1] + bcol);
            o.z = f2bf(acc[2] + bcol); o.w = f2bf(acc[3] + bcol);
            *reinterpret_cast<ushort4*>(Vs + off) = o;
        }
    }
}

#define SL(j, offs) asm("s_load_dwordx2 %0, %1, " offs : "=s"(m##j) : "s"(mbase))
#define SLOAD16() do { \
    SL(0, "0x0");  SL(1, "0x8");  SL(2, "0x10"); SL(3, "0x18"); \
    SL(4, "0x20"); SL(5, "0x28"); SL(6, "0x30"); SL(7, "0x38"); \
    SL(8, "0x40"); SL(9, "0x48"); SL(10, "0x50"); SL(11, "0x58"); \
    SL(12, "0x60"); SL(13, "0x68"); SL(14, "0x70"); SL(15, "0x78"); } while (0)
#define CND(d, s_, mj) asm("v_cndmask_b32 %0, 0, %1, %2" : "=v"(d) : "v"(s_), "s"(mj))

// ---------------- masked attention (R17/R19 best: 256-thr blocks, 5 waves/SIMD) ----------------
__global__ __launch_bounds__(256, 5) void k_attn(const unsigned short* __restrict__ Qts,
                                                 const unsigned short* __restrict__ Kb,
                                                 const unsigned short* __restrict__ Vs,
                                                 const unsigned int* __restrict__ mbgT2,
                                                 unsigned short* __restrict__ att) {
    int tid = threadIdx.x;
    int lane = tid & 63;
    int l31 = lane & 31, hi = lane >> 5;
    int b = blockIdx.x & 7;
    int hg = (blockIdx.x >> 3) & 1;
    int qt32 = blockIdx.x >> 4;
    int q0 = qt32 * 32;
    int head = hg * 4 + (tid >> 6);
    int bh = b * 8 + head;

    const unsigned short* Qh = Qts + (size_t)bh * 65536 + (size_t)qt32 * 1024 + (size_t)lane * 8;
    const unsigned short* Kh = Kb + (size_t)bh * 65536;
    const unsigned short* Vh = Vs + (size_t)bh * 65536;

    short8 qf0 = *reinterpret_cast<const short8*>(Qh);
    short8 qf1 = *reinterpret_cast<const short8*>(Qh + 512);
    const unsigned short* krow = Kh + (size_t)lane * 8;
    const unsigned short* vfp = Vh + (size_t)lane * 8;

    unsigned long long mbase = (unsigned long long)(mbgT2 + (size_t)(b * 64 + qt32) * 2048);
    unsigned long long m0, m1, m2, m3, m4, m5, m6, m7, m8, m9, m10, m11, m12, m13, m14, m15;
    SLOAD16();   // tile 0 lane masks in flight

    const f32x16 fz = {0.f,0.f,0.f,0.f,0.f,0.f,0.f,0.f,0.f,0.f,0.f,0.f,0.f,0.f,0.f,0.f};
    f32x16 attacc = fz;
    float lsum = 0.f;

#pragma unroll 2
    for (int t = 0; t < 64; ++t) {
        short8 kf0 = *reinterpret_cast<const short8*>(krow + (size_t)t * 1024);
        short8 kf1 = *reinterpret_cast<const short8*>(krow + (size_t)t * 1024 + 512);
        short8 vf0 = *reinterpret_cast<const short8*>(vfp + (size_t)t * 1024);
        short8 vf1 = *reinterpret_cast<const short8*>(vfp + (size_t)t * 1024 + 512);

        f32x16 s = __builtin_amdgcn_mfma_f32_32x32x16_bf16(kf0, qf0, fz, 0, 0, 0);
        s = __builtin_amdgcn_mfma_f32_32x32x16_bf16(kf1, qf1, s, 0, 0, 0);

        float e0 = exp2v(s[0]),  e1 = exp2v(s[1]),  e2 = exp2v(s[2]),  e3 = exp2v(s[3]);
        float e4 = exp2v(s[4]),  e5 = exp2v(s[5]),  e6 = exp2v(s[6]),  e7 = exp2v(s[7]);
        float e8 = exp2v(s[8]),  e9 = exp2v(s[9]),  e10 = exp2v(s[10]), e11 = exp2v(s[11]);
        float e12 = exp2v(s[12]), e13 = exp2v(s[13]), e14 = exp2v(s[14]), e15 = exp2v(s[15]);

        asm volatile("s_waitcnt lgkmcnt(0)"
                     : "+s"(m0), "+s"(m1), "+s"(m2), "+s"(m3), "+s"(m4), "+s"(m5), "+s"(m6), "+s"(m7),
                       "+s"(m8), "+s"(m9), "+s"(m10), "+s"(m11), "+s"(m12), "+s"(m13), "+s"(m14), "+s"(m15));

        float p0, p1, p2, p3, p4, p5, p6, p7, p8, p9, p10, p11, p12, p13, p14, p15;
        CND(p0, e0, m0);   CND(p1, e1, m1);   CND(p2, e2, m2);   CND(p3, e3, m3);
        CND(p4, e4, m4);   CND(p5, e5, m5);   CND(p6, e6, m6);   CND(p7, e7, m7);
        CND(p8, e8, m8);   CND(p9, e9, m9);   CND(p10, e10, m10); CND(p11, e11, m11);
        CND(p12, e12, m12); CND(p13, e13, m13); CND(p14, e14, m14); CND(p15, e15, m15);

        lsum += ((p0 + p1) + (p2 + p3)) + ((p4 + p5) + (p6 + p7))
              + ((p8 + p9) + (p10 + p11)) + ((p12 + p13) + (p14 + p15));

        unsigned int pd[4][2];
        pd[0][0] = cvtpk(p0, p1);   pd[0][1] = cvtpk(p2, p3);
        pd[1][0] = cvtpk(p4, p5);   pd[1][1] = cvtpk(p6, p7);
        pd[2][0] = cvtpk(p8, p9);   pd[2][1] = cvtpk(p10, p11);
        pd[3][0] = cvtpk(p12, p13); pd[3][1] = cvtpk(p14, p15);

        mbase += 128;
        SLOAD16();   // masks for tile t+1 (t=63 reads pad)

        asm("v_permlane32_swap_b32 %0, %1" : "+v"(pd[0][0]), "+v"(pd[1][0]));
        asm("v_permlane32_swap_b32 %0, %1" : "+v"(pd[0][1]), "+v"(pd[1][1]));
        asm("v_permlane32_swap_b32 %0, %1" : "+v"(pd[2][0]), "+v"(pd[3][0]));
        asm("v_permlane32_swap_b32 %0, %1" : "+v"(pd[2][1]), "+v"(pd[3][1]));

        union { short8 s8; unsigned int u[4]; } bf0, bf1;
        bf0.u[0] = pd[0][0]; bf0.u[1] = pd[0][1]; bf0.u[2] = pd[1][0]; bf0.u[3] = pd[1][1];
        bf1.u[0] = pd[2][0]; bf1.u[1] = pd[2][1]; bf1.u[2] = pd[3][0]; bf1.u[3] = pd[3][1];

        attacc = __builtin_amdgcn_mfma_f32_32x32x16_bf16(vf0, bf0.s8, attacc, 0, 0, 0);
        attacc = __builtin_amdgcn_mfma_f32_32x32x16_bf16(vf1, bf1.s8, attacc, 0, 0, 0);
    }

    lsum += __shfl_xor(lsum, 32, 64);
    float rcp = 1.f / lsum;

    unsigned short* arow = att + ((size_t)b * N_ + q0 + l31) * D_ + head * HD_;
#pragma unroll
    for (int g = 0; g < 4; ++g) {
        ushort4 o;
        o.x = f2bf(attacc[4 * g + 0] * rcp);
        o.y = f2bf(attacc[4 * g + 1] * rcp);
        o.z = f2bf(attacc[4 * g + 2] * rcp);
        o.w = f2bf(attacc[4 * g + 3] * rcp);
        *reinterpret_cast<ushort4*>(arow + 8 * g + 4 * hi) = o;
    }
}

// ---------------- out projection + residual + LayerNorm (vectorized) ----------------
__global__ __launch_bounds__(256) void k_outln(const unsigned short* __restrict__ att,
                                               const unsigned short* __restrict__ wot,
                                               const float* __restrict__ bo,
                                               const float* __restrict__ x,
                                               const float* __restrict__ gamma, const float* __restrict__ beta,
                                               float* __restrict__ out) {
    int lane = threadIdx.x & 63, wv = threadIdx.x >> 6;
    int l15 = lane & 15, lg = lane >> 4;
    int row0 = blockIdx.x * 64 + wv * 16;
    size_t row = (size_t)(row0 + l15);

    short8 af[8];
    const unsigned short* arow = att + row * 256 + lg * 8;
#pragma unroll
    for (int kk = 0; kk < 8; ++kk)
        af[kk] = *reinterpret_cast<const short8*>(arow + kk * 32);

    float v[16][4];
    float sum = 0.f, sq = 0.f;
#pragma unroll
    for (int ci = 0; ci < 16; ++ci) {
        const unsigned short* wrow = wot + (size_t)(ci * 16 + l15) * 256 + lg * 8;
        f32x4 acc = {0.f, 0.f, 0.f, 0.f};
#pragma unroll
        for (int kk = 0; kk < 8; ++kk) {
            short8 bfg = *reinterpret_cast<const short8*>(wrow + kk * 32);
            acc = __builtin_amdgcn_mfma_f32_16x16x32_bf16(bfg, af[kk], acc, 0, 0, 0);
        }
        int col0 = ci * 16 + lg * 4;
        float4 b4 = *reinterpret_cast<const float4*>(bo + col0);
        float4 x4 = *reinterpret_cast<const float4*>(x + row * 256 + col0);
        v[ci][0] = acc[0] + b4.x + x4.x;
        v[ci][1] = acc[1] + b4.y + x4.y;
        v[ci][2] = acc[2] + b4.z + x4.z;
        v[ci][3] = acc[3] + b4.w + x4.w;
#pragma unroll
        for (int r = 0; r < 4; ++r) {
            sum += v[ci][r];
            sq += v[ci][r] * v[ci][r];
        }
    }

    sum += __shfl_xor(sum, 16, 64); sq += __shfl_xor(sq, 16, 64);
    sum += __shfl_xor(sum, 32, 64); sq += __shfl_xor(sq, 32, 64);

    float mu = sum * (1.f / 256.f);
    float var = sq * (1.f / 256.f) - mu * mu;
    float rs = rsqrtf(var + LN_EPS);

#pragma unroll
    for (int ci = 0; ci < 16; ++ci) {
        int col0 = ci * 16 + lg * 4;
        float4 g4 = *reinterpret_cast<const float4*>(gamma + col0);
        float4 be4 = *reinterpret_cast<const float4*>(beta + col0);
        float4 o;
        o.x = (v[ci][0] - mu) * rs * g4.x + be4.x;
        o.y = (v[ci][1] - mu) * rs * g4.y + be4.y;
        o.z = (v[ci][2] - mu) * rs * g4.z + be4.z;
        o.w = (v[ci][3] - mu) * rs * g4.w + be4.w;
        *reinterpret_cast<float4*>(out + row * 256 + col0) = o;
    }
}

extern "C" void kernel_launch(void* const* d_in, const int* in_sizes, int n_in,
                              void* d_out, int out_size, void* d_ws, size_t ws_size,
                              hipStream_t stream) {
    (void)in_sizes; (void)n_in; (void)out_size; (void)ws_size;
    const float* x     = (const float*)d_in[0];
    const int*   adj   = (const int*)d_in[1];
    const float* Wq    = (const float*)d_in[2];
    const float* bq    = (const float*)d_in[3];
    const float* Wk    = (const float*)d_in[4];
    const float* bk    = (const float*)d_in[5];
    const float* Wv    = (const float*)d_in[6];
    const float* bv    = (const float*)d_in[7];
    const float* Wo    = (const float*)d_in[8];
    const float* bo    = (const float*)d_in[9];
    const float* gamma = (const float*)d_in[10];
    const float* beta  = (const float*)d_in[11];
    float* out = (float*)d_out;

    char* ws = (char*)d_ws;
    unsigned short* wt   = (unsigned short*)ws; ws += (size_t)4 * 256 * 256 * 2; // 0.5 MB
    unsigned short* Qts  = (unsigned short*)ws; ws += (size_t)B_ * H_ * N_ * HD_ * 2; // 8.4 MB
    unsigned short* Ks   = (unsigned short*)ws; ws += (size_t)B_ * H_ * N_ * HD_ * 2;
    unsigned short* Vs   = (unsigned short*)ws; ws += (size_t)B_ * H_ * N_ * HD_ * 2;
    unsigned short* att  = (unsigned short*)ws; ws += (size_t)16384 * 256 * 2;
    unsigned int*   mbgT2 = (unsigned int*)ws;  ws += (size_t)B_ * 64 * 2048 * 4 + 8192; // 4.2 MB + pad

    k_prep_w<<<dim3(256, 4), 256, 0, stream>>>(Wq, Wk, Wv, Wo, wt);
    k_maskF<<<256, 512, 0, stream>>>(adj, mbgT2);
    k_qkv<<<dim3(256, 3), 256, 0, stream>>>(x, wt, bq, bk, bv, Qts, Ks, Vs);
    k_attn<<<1024, 256, 0, stream>>>(Qts, Ks, Vs, mbgT2, att);
    k_outln<<<256, 256, 0, stream>>>(att, wt + 3 * 65536, bo, x, gamma, beta, out);
}

// Round 22
// 152.420 us; speedup vs baseline: 1.3746x; 1.1544x over previous
//
#include <hip/hip_runtime.h>
#include <hip/hip_bf16.h>
#include <cstdint>
#include <cstddef>

// Problem constants
#define B_ 8
#define N_ 2048
#define D_ 256
#define H_ 8
#define HD_ 32
#define LN_EPS 1e-5f
#define QSCALE 0.25506275f  // log2(e)/sqrt(32): folded into Q so p = exp2(q'.k)

typedef __attribute__((ext_vector_type(8))) short short8;
typedef __attribute__((ext_vector_type(4))) float f32x4;
typedef __attribute__((ext_vector_type(16))) float f32x16;

static __device__ __forceinline__ float exp2v(float x) {
#if __has_builtin(__builtin_amdgcn_exp2f)
    return __builtin_amdgcn_exp2f(x);
#else
    float r;
    asm("v_exp_f32 %0, %1" : "=v"(r) : "v"(x));
    return r;
#endif
}

static __device__ __forceinline__ unsigned short f2bf(float f) {
    union { float f; unsigned int u; } v; v.f = f;
    unsigned int r = v.u + 0x7fffu + ((v.u >> 16) & 1u);
    return (unsigned short)(r >> 16);
}

static __device__ __forceinline__ unsigned int cvtpk(float lo, float hi) {
    unsigned int d;
    asm("v_cvt_pk_bf16_f32 %0, %1, %2" : "=v"(d) : "v"(lo), "v"(hi));
    return d;
}

// ---------------- prep: W fp32 -> bf16 transposed wt[mat][col][k] ----------------
__global__ __launch_bounds__(256) void k_prep_w(const float* __restrict__ w0, const float* __restrict__ w1,
                                                const float* __restrict__ w2, const float* __restrict__ w3,
                                                unsigned short* __restrict__ wt) {
    int c = blockIdx.x, mat = blockIdx.y, k = threadIdx.x;
    const float* w = (mat == 0) ? w0 : (mat == 1) ? w1 : (mat == 2) ? w2 : w3;
    wt[((size_t)(mat * 256 + c)) * 256 + k] = f2bf(w[k * 256 + c]);
}

// ---------------- MERGED mask + qkv (heterogeneous co-scheduling) ----------------
// Blocks 0..255: adjacency -> transposed lane-mask (memory/latency-bound).
// Blocks 256..1023: QKV projection GEMM (MFMA-bound), bid-256 = mat*256 + blk.
// The two are data-independent; co-residency overlaps HBM streaming with MFMA.
__global__ __launch_bounds__(256) void k_mq(const int* __restrict__ adj,
                                            unsigned int* __restrict__ mbgT2,
                                            const float* __restrict__ x,
                                            const unsigned short* __restrict__ wt,
                                            const float* __restrict__ bq, const float* __restrict__ bk,
                                            const float* __restrict__ bv,
                                            unsigned short* __restrict__ Qts, unsigned short* __restrict__ Ks,
                                            unsigned short* __restrict__ Vs) {
    __shared__ unsigned int bits[64][66];
    int tid = threadIdx.x;
    int lane = tid & 63, wv = tid >> 6;

    if (blockIdx.x < 256) {
        // ---- mask path (R15 256-thread form: 64 rows/block, 16 rows/wave) ----
        int b = blockIdx.x >> 5, rg = blockIdx.x & 31;
        const int* base = adj + ((size_t)(b * N_ + rg * 64 + wv * 16)) * N_ + lane;
#pragma unroll 1
        for (int i = 0; i < 16; ++i) {
            const int* prow = base + (size_t)i * N_;
#pragma unroll
            for (int half = 0; half < 2; ++half) {
                int v[16];
#pragma unroll
                for (int j = 0; j < 16; ++j)
                    v[j] = prow[half * 1024 + j * 64];
                __builtin_amdgcn_sched_barrier(0);
#pragma unroll
                for (int j = 0; j < 16; ++j) {
                    unsigned long long m = __ballot(v[j] != 0);
                    if (lane == 0)
                        *reinterpret_cast<unsigned long long*>(&bits[wv * 16 + i][half * 32 + 2 * j]) = m;
                }
            }
        }
        __syncthreads();

        int h = lane >> 5, l31 = lane & 31;
        const unsigned int M[5] = {0x0000FFFFu, 0x00FF00FFu, 0x0F0F0F0Fu, 0x33333333u, 0x55555555u};
#pragma unroll
        for (int j = 0; j < 16; ++j) {
            int kw = wv * 16 + j;
            unsigned int w = bits[lane][kw];
#pragma unroll
            for (int si = 0; si < 5; ++si) {
                int s = 16 >> si;
                unsigned int m = M[si];
                unsigned int t = (unsigned int)__shfl_xor((int)w, s, 64);
                unsigned int a = (w & m) | ((t & m) << s);
                unsigned int c = (w & ~m) | ((t >> s) & m);
                w = (lane & s) ? c : a;
            }
            int k = kw * 32 + l31;
            int kp = (k & ~7) | ((k & 3) << 1) | ((k >> 2) & 1);
            mbgT2[((size_t)(b * 64 + rg * 2 + h)) * 2048 + kp] = w;
        }
        return;
    }

    // ---- qkv path ----
    int bid = blockIdx.x - 256;
    int mat = bid >> 8;
    int blkx = bid & 255;
    int row0 = blkx * 64 + wv * 16;
    int l15 = lane & 15, lg = lane >> 4;
    const float* bias = (mat == 0) ? bq : (mat == 1) ? bk : bv;
    const float qs = (mat == 0) ? QSCALE : 1.0f;
    const unsigned short* wm = wt + (size_t)mat * 65536;

    short8 af[8];
    const float* xrow = x + (size_t)(row0 + l15) * 256 + lg * 8;
#pragma unroll
    for (int kk = 0; kk < 8; ++kk) {
        float4 a = *reinterpret_cast<const float4*>(xrow + kk * 32);
        float4 b = *reinterpret_cast<const float4*>(xrow + kk * 32 + 4);
        union { short8 s8; unsigned int u[4]; } t;
        t.u[0] = cvtpk(a.x, a.y); t.u[1] = cvtpk(a.z, a.w);
        t.u[2] = cvtpk(b.x, b.y); t.u[3] = cvtpk(b.z, b.w);
        af[kk] = t.s8;
    }

    int b = row0 >> 11;            // 2048 rows per batch; 64-row blocks never cross
    int nbase = (row0 & 2047) + lg * 4;

    if (mat < 2) {
        unsigned short* dst = (mat == 0) ? Qts : Ks;
        int n = (row0 & 2047) + l15;          // lane's row
        for (int ci = 0; ci < 16; ++ci) {
            const unsigned short* wrow = wm + (size_t)(ci * 16 + l15) * 256 + lg * 8;
            f32x4 acc = {0.f, 0.f, 0.f, 0.f};
#pragma unroll
            for (int kk = 0; kk < 8; ++kk) {
                short8 bfg = *reinterpret_cast<const short8*>(wrow + kk * 32);
                acc = __builtin_amdgcn_mfma_f32_16x16x32_bf16(bfg, af[kk], acc, 0, 0, 0);
            }
            int col0 = ci * 16 + lg * 4;
            float4 b4 = *reinterpret_cast<const float4*>(bias + col0);
            int h = col0 >> 5;
            int hd0 = col0 & 31;
            size_t off = (size_t)(b * 8 + h) * 65536 + (size_t)(n >> 5) * 1024
                       + (size_t)(hd0 >> 4) * 512
                       + (size_t)((((hd0 >> 3) & 1) * 32 + (n & 31))) * 8 + (hd0 & 7);
            ushort4 o;
            o.x = f2bf((acc[0] + b4.x) * qs); o.y = f2bf((acc[1] + b4.y) * qs);
            o.z = f2bf((acc[2] + b4.z) * qs); o.w = f2bf((acc[3] + b4.w) * qs);
            *reinterpret_cast<ushort4*>(dst + off) = o;
        }
    } else {
        for (int ci = 0; ci < 16; ++ci) {
            const unsigned short* wrow = wm + (size_t)(ci * 16 + l15) * 256 + lg * 8;
            f32x4 acc = {0.f, 0.f, 0.f, 0.f};
#pragma unroll
            for (int kk = 0; kk < 8; ++kk) {
                short8 bfg = *reinterpret_cast<const short8*>(wrow + kk * 32);
                acc = __builtin_amdgcn_mfma_f32_16x16x32_bf16(af[kk], bfg, acc, 0, 0, 0);
            }
            int col = ci * 16 + l15;
            float bcol = bias[col];
            int h = col >> 5, hd = col & 31;
            int posb = nbase & 31;
            size_t off = (size_t)(b * 8 + h) * 65536 + (size_t)(nbase >> 5) * 1024
                       + (posb >> 4) * 512 + ((((posb >> 3) & 1) * 32 + hd)) * 8 + (posb & 7);
            ushort4 o;
            o.x = f2bf(acc[0] + bcol); o.y = f2bf(acc[1] + bcol);
            o.z = f2bf(acc[2] + bcol); o.w = f2bf(acc[3] + bcol);
            *reinterpret_cast<ushort4*>(Vs + off) = o;
        }
    }
}

#define SL(j, offs) asm("s_load_dwordx2 %0, %1, " offs : "=s"(m##j) : "s"(mbase))
#define SLOAD16() do { \
    SL(0, "0x0");  SL(1, "0x8");  SL(2, "0x10"); SL(3, "0x18"); \
    SL(4, "0x20"); SL(5, "0x28"); SL(6, "0x30"); SL(7, "0x38"); \
    SL(8, "0x40"); SL(9, "0x48"); SL(10, "0x50"); SL(11, "0x58"); \
    SL(12, "0x60"); SL(13, "0x68"); SL(14, "0x70"); SL(15, "0x78"); } while (0)
#define CND(d, s_, mj) asm("v_cndmask_b32 %0, 0, %1, %2" : "=v"(d) : "v"(s_), "s"(mj))

// ---------------- masked attention (R17/R19 best: 256-thr blocks, 5 waves/SIMD) ----------------
__global__ __launch_bounds__(256, 5) void k_attn(const unsigned short* __restrict__ Qts,
                                                 const unsigned short* __restrict__ Kb,
                                                 const unsigned short* __restrict__ Vs,
                                                 const unsigned int* __restrict__ mbgT2,
                                                 unsigned short* __restrict__ att) {
    int tid = threadIdx.x;
    int lane = tid & 63;
    int l31 = lane & 31, hi = lane >> 5;
    int b = blockIdx.x & 7;
    int hg = (blockIdx.x >> 3) & 1;
    int qt32 = blockIdx.x >> 4;
    int q0 = qt32 * 32;
    int head = hg * 4 + (tid >> 6);
    int bh = b * 8 + head;

    const unsigned short* Qh = Qts + (size_t)bh * 65536 + (size_t)qt32 * 1024 + (size_t)lane * 8;
    const unsigned short* Kh = Kb + (size_t)bh * 65536;
    const unsigned short* Vh = Vs + (size_t)bh * 65536;

    short8 qf0 = *reinterpret_cast<const short8*>(Qh);
    short8 qf1 = *reinterpret_cast<const short8*>(Qh + 512);
    const unsigned short* krow = Kh + (size_t)lane * 8;
    const unsigned short* vfp = Vh + (size_t)lane * 8;

    unsigned long long mbase = (unsigned long long)(mbgT2 + (size_t)(b * 64 + qt32) * 2048);
    unsigned long long m0, m1, m2, m3, m4, m5, m6, m7, m8, m9, m10, m11, m12, m13, m14, m15;
    SLOAD16();   // tile 0 lane masks in flight

    const f32x16 fz = {0.f,0.f,0.f,0.f,0.f,0.f,0.f,0.f,0.f,0.f,0.f,0.f,0.f,0.f,0.f,0.f};
    f32x16 attacc = fz;
    float lsum = 0.f;

#pragma unroll 2
    for (int t = 0; t < 64; ++t) {
        short8 kf0 = *reinterpret_cast<const short8*>(krow + (size_t)t * 1024);
        short8 kf1 = *reinterpret_cast<const short8*>(krow + (size_t)t * 1024 + 512);
        short8 vf0 = *reinterpret_cast<const short8*>(vfp + (size_t)t * 1024);
        short8 vf1 = *reinterpret_cast<const short8*>(vfp + (size_t)t * 1024 + 512);

        f32x16 s = __builtin_amdgcn_mfma_f32_32x32x16_bf16(kf0, qf0, fz, 0, 0, 0);
        s = __builtin_amdgcn_mfma_f32_32x32x16_bf16(kf1, qf1, s, 0, 0, 0);

        float e0 = exp2v(s[0]),  e1 = exp2v(s[1]),  e2 = exp2v(s[2]),  e3 = exp2v(s[3]);
        float e4 = exp2v(s[4]),  e5 = exp2v(s[5]),  e6 = exp2v(s[6]),  e7 = exp2v(s[7]);
        float e8 = exp2v(s[8]),  e9 = exp2v(s[9]),  e10 = exp2v(s[10]), e11 = exp2v(s[11]);
        float e12 = exp2v(s[12]), e13 = exp2v(s[13]), e14 = exp2v(s[14]), e15 = exp2v(s[15]);

        asm volatile("s_waitcnt lgkmcnt(0)"
                     : "+s"(m0), "+s"(m1), "+s"(m2), "+s"(m3), "+s"(m4), "+s"(m5), "+s"(m6), "+s"(m7),
                       "+s"(m8), "+s"(m9), "+s"(m10), "+s"(m11), "+s"(m12), "+s"(m13), "+s"(m14), "+s"(m15));

        float p0, p1, p2, p3, p4, p5, p6, p7, p8, p9, p10, p11, p12, p13, p14, p15;
        CND(p0, e0, m0);   CND(p1, e1, m1);   CND(p2, e2, m2);   CND(p3, e3, m3);
        CND(p4, e4, m4);   CND(p5, e5, m5);   CND(p6, e6, m6);   CND(p7, e7, m7);
        CND(p8, e8, m8);   CND(p9, e9, m9);   CND(p10, e10, m10); CND(p11, e11, m11);
        CND(p12, e12, m12); CND(p13, e13, m13); CND(p14, e14, m14); CND(p15, e15, m15);

        lsum += ((p0 + p1) + (p2 + p3)) + ((p4 + p5) + (p6 + p7))
              + ((p8 + p9) + (p10 + p11)) + ((p12 + p13) + (p14 + p15));

        unsigned int pd[4][2];
        pd[0][0] = cvtpk(p0, p1);   pd[0][1] = cvtpk(p2, p3);
        pd[1][0] = cvtpk(p4, p5);   pd[1][1] = cvtpk(p6, p7);
        pd[2][0] = cvtpk(p8, p9);   pd[2][1] = cvtpk(p10, p11);
        pd[3][0] = cvtpk(p12, p13); pd[3][1] = cvtpk(p14, p15);

        mbase += 128;
        SLOAD16();   // masks for tile t+1 (t=63 reads pad)

        asm("v_permlane32_swap_b32 %0, %1" : "+v"(pd[0][0]), "+v"(pd[1][0]));
        asm("v_permlane32_swap_b32 %0, %1" : "+v"(pd[0][1]), "+v"(pd[1][1]));
        asm("v_permlane32_swap_b32 %0, %1" : "+v"(pd[2][0]), "+v"(pd[3][0]));
        asm("v_permlane32_swap_b32 %0, %1" : "+v"(pd[2][1]), "+v"(pd[3][1]));

        union { short8 s8; unsigned int u[4]; } bf0, bf1;
        bf0.u[0] = pd[0][0]; bf0.u[1] = pd[0][1]; bf0.u[2] = pd[1][0]; bf0.u[3] = pd[1][1];
        bf1.u[0] = pd[2][0]; bf1.u[1] = pd[2][1]; bf1.u[2] = pd[3][0]; bf1.u[3] = pd[3][1];

        attacc = __builtin_amdgcn_mfma_f32_32x32x16_bf16(vf0, bf0.s8, attacc, 0, 0, 0);
        attacc = __builtin_amdgcn_mfma_f32_32x32x16_bf16(vf1, bf1.s8, attacc, 0, 0, 0);
    }

    lsum += __shfl_xor(lsum, 32, 64);
    float rcp = 1.f / lsum;

    unsigned short* arow = att + ((size_t)b * N_ + q0 + l31) * D_ + head * HD_;
#pragma unroll
    for (int g = 0; g < 4; ++g) {
        ushort4 o;
        o.x = f2bf(attacc[4 * g + 0] * rcp);
        o.y = f2bf(attacc[4 * g + 1] * rcp);
        o.z = f2bf(attacc[4 * g + 2] * rcp);
        o.w = f2bf(attacc[4 * g + 3] * rcp);
        *reinterpret_cast<ushort4*>(arow + 8 * g + 4 * hi) = o;
    }
}

// ---------------- out projection + residual + LayerNorm (vectorized) ----------------
__global__ __launch_bounds__(256) void k_outln(const unsigned short* __restrict__ att,
                                               const unsigned short* __restrict__ wot,
                                               const float* __restrict__ bo,
                                               const float* __restrict__ x,
                                               const float* __restrict__ gamma, const float* __restrict__ beta,
                                               float* __restrict__ out) {
    int lane = threadIdx.x & 63, wv = threadIdx.x >> 6;
    int l15 = lane & 15, lg = lane >> 4;
    int row0 = blockIdx.x * 64 + wv * 16;
    size_t row = (size_t)(row0 + l15);

    short8 af[8];
    const unsigned short* arow = att + row * 256 + lg * 8;
#pragma unroll
    for (int kk = 0; kk < 8; ++kk)
        af[kk] = *reinterpret_cast<const short8*>(arow + kk * 32);

    float v[16][4];
    float sum = 0.f, sq = 0.f;
#pragma unroll
    for (int ci = 0; ci < 16; ++ci) {
        const unsigned short* wrow = wot + (size_t)(ci * 16 + l15) * 256 + lg * 8;
        f32x4 acc = {0.f, 0.f, 0.f, 0.f};
#pragma unroll
        for (int kk = 0; kk < 8; ++kk) {
            short8 bfg = *reinterpret_cast<const short8*>(wrow + kk * 32);
            acc = __builtin_amdgcn_mfma_f32_16x16x32_bf16(bfg, af[kk], acc, 0, 0, 0);
        }
        int col0 = ci * 16 + lg * 4;
        float4 b4 = *reinterpret_cast<const float4*>(bo + col0);
        float4 x4 = *reinterpret_cast<const float4*>(x + row * 256 + col0);
        v[ci][0] = acc[0] + b4.x + x4.x;
        v[ci][1] = acc[1] + b4.y + x4.y;
        v[ci][2] = acc[2] + b4.z + x4.z;
        v[ci][3] = acc[3] + b4.w + x4.w;
#pragma unroll
        for (int r = 0; r < 4; ++r) {
            sum += v[ci][r];
            sq += v[ci][r] * v[ci][r];
        }
    }

    sum += __shfl_xor(sum, 16, 64); sq += __shfl_xor(sq, 16, 64);
    sum += __shfl_xor(sum, 32, 64); sq += __shfl_xor(sq, 32, 64);

    float mu = sum * (1.f / 256.f);
    float var = sq * (1.f / 256.f) - mu * mu;
    float rs = rsqrtf(var + LN_EPS);

#pragma unroll
    for (int ci = 0; ci < 16; ++ci) {
        int col0 = ci * 16 + lg * 4;
        float4 g4 = *reinterpret_cast<const float4*>(gamma + col0);
        float4 be4 = *reinterpret_cast<const float4*>(beta + col0);
        float4 o;
        o.x = (v[ci][0] - mu) * rs * g4.x + be4.x;
        o.y = (v[ci][1] - mu) * rs * g4.y + be4.y;
        o.z = (v[ci][2] - mu) * rs * g4.z + be4.z;
        o.w = (v[ci][3] - mu) * rs * g4.w + be4.w;
        *reinterpret_cast<float4*>(out + row * 256 + col0) = o;
    }
}

extern "C" void kernel_launch(void* const* d_in, const int* in_sizes, int n_in,
                              void* d_out, int out_size, void* d_ws, size_t ws_size,
                              hipStream_t stream) {
    (void)in_sizes; (void)n_in; (void)out_size; (void)ws_size;
    const float* x     = (const float*)d_in[0];
    const int*   adj   = (const int*)d_in[1];
    const float* Wq    = (const float*)d_in[2];
    const float* bq    = (const float*)d_in[3];
    const float* Wk    = (const float*)d_in[4];
    const float* bk    = (const float*)d_in[5];
    const float* Wv    = (const float*)d_in[6];
    const float* bv    = (const float*)d_in[7];
    const float* Wo    = (const float*)d_in[8];
    const float* bo    = (const float*)d_in[9];
    const float* gamma = (const float*)d_in[10];
    const float* beta  = (const float*)d_in[11];
    float* out = (float*)d_out;

    char* ws = (char*)d_ws;
    unsigned short* wt   = (unsigned short*)ws; ws += (size_t)4 * 256 * 256 * 2; // 0.5 MB
    unsigned short* Qts  = (unsigned short*)ws; ws += (size_t)B_ * H_ * N_ * HD_ * 2; // 8.4 MB
    unsigned short* Ks   = (unsigned short*)ws; ws += (size_t)B_ * H_ * N_ * HD_ * 2;
    unsigned short* Vs   = (unsigned short*)ws; ws += (size_t)B_ * H_ * N_ * HD_ * 2;
    unsigned short* att  = (unsigned short*)ws; ws += (size_t)16384 * 256 * 2;
    unsigned int*   mbgT2 = (unsigned int*)ws;  ws += (size_t)B_ * 64 * 2048 * 4 + 8192; // 4.2 MB + pad

    k_prep_w<<<dim3(256, 4), 256, 0, stream>>>(Wq, Wk, Wv, Wo, wt);
    k_mq<<<1024, 256, 0, stream>>>(adj, mbgT2, x, wt, bq, bk, bv, Qts, Ks, Vs);
    k_attn<<<1024, 256, 0, stream>>>(Qts, Ks, Vs, mbgT2, att);
    k_outln<<<256, 256, 0, stream>>>(att, wt + 3 * 65536, bo, x, gamma, beta, out);
}